// Round 3
// baseline (41346.271 us; speedup 1.0000x reference)
//
#include <hip/hip_runtime.h>
#include <hip/hip_bf16.h>

// ============================================================================
// Seq2Seq (Graves handwriting) forward on MI355X — Round 2.
// Persistent scan kernel, 100 blocks x 512 thr. 3 fence-free global barriers
// per step. Cross-block state via device-scope (sc1, LLC-coherent) relaxed
// atomics -> NO buffer_wbl2/buffer_inv -> weights stay L2-resident.
// Single-wave attention overlapped with LDS h-prestage.
// ============================================================================

#define B_ 64
#define T_ 400
#define U_ 64
#define E_ 128
#define H_ 400
#define M_ 10
#define NO_ 121

#define NBLK 100
#define NTHR 512

// ---------------- ws layout (float units) ----------------
// words 0..127 = control: cnt@0, gen@32, lossS@64, lossE@65
constexpr size_t OF_WS2  = 128;                   // w state [64][128]      (sc1)
constexpr size_t OF_KS   = OF_WS2 + 64*128;       // kappa [64][10]         (private)
constexpr size_t OF_N0H  = OF_KS + 640;           // n0h [b][400]           (sc1)
constexpr size_t OF_N0C  = OF_N0H + 25600;        // n0c [n][64]            (private)
constexpr size_t OF_N1H  = OF_N0C + 25600;        // n1h [b][400]           (sc1)
constexpr size_t OF_N1C  = OF_N1H + 25600;        // n1c [n][64]            (private)
constexpr size_t OF_HA   = OF_N1C + 25600;        // hA  [b][400]           (sc1)
constexpr size_t OF_B0   = OF_HA + 25600;         // bias0 [1600]
constexpr size_t OF_B1   = OF_B0 + 1600;          // bias1 + h2c@Wih1[:,131:531]
constexpr size_t OF_B2   = OF_B1 + 1600;          // bias2 + h2c@Whh2
constexpr size_t OF_OB   = OF_B2 + 1600;          // obias [121] (+pad)
constexpr size_t OF_XT   = OF_OB + 128;           // xT [t][3][64]
constexpr size_t OF_CTX  = OF_XT + (size_t)T_*3*64;     // ctx [b][u][e]
constexpr size_t OF_A0   = OF_CTX + (size_t)64*64*128;  // bf16 n0h_all [t][b][400]
constexpr size_t OF_A1   = OF_A0 + (size_t)T_*64*400/2; // bf16 n1h_all
constexpr size_t WS_FLOATS = OF_A1 + (size_t)T_*64*400/2;

__device__ __forceinline__ float sigf(float x) { return 1.f/(1.f + expf(-x)); }

// ---------------- device-scope (LLC-coherent, L2-bypassing) state access ----
__device__ __forceinline__ float ld_dev(const float* p) {
  unsigned v = __hip_atomic_load((const unsigned*)p, __ATOMIC_RELAXED, __HIP_MEMORY_SCOPE_AGENT);
  return __uint_as_float(v);
}
__device__ __forceinline__ float2 ld_dev2(const float* p) {
  unsigned long long v = __hip_atomic_load((const unsigned long long*)p, __ATOMIC_RELAXED, __HIP_MEMORY_SCOPE_AGENT);
  union { unsigned long long u; float2 f; } c; c.u = v; return c.f;
}
__device__ __forceinline__ void st_dev(float* p, float v) {
  __hip_atomic_store((unsigned*)p, __float_as_uint(v), __ATOMIC_RELAXED, __HIP_MEMORY_SCOPE_AGENT);
}

// ---------------- fence-free global barrier ----------------
// All cross-block data moves via sc1 (device-scope) ops, so no cache
// maintenance is needed here. Entry __syncthreads drains vmcnt (store
// visibility); arrival/spin are relaxed LLC atomics.
__device__ __forceinline__ void gbar(unsigned* cnt, unsigned* gen, unsigned tgt) {
  __syncthreads();
  if (threadIdx.x == 0) {
    unsigned prev = __hip_atomic_fetch_add(cnt, 1u, __ATOMIC_RELAXED, __HIP_MEMORY_SCOPE_AGENT);
    if (prev == tgt*(unsigned)NBLK - 1u) {
      __hip_atomic_store(gen, tgt, __ATOMIC_RELAXED, __HIP_MEMORY_SCOPE_AGENT);
    } else {
      while (__hip_atomic_load(gen, __ATOMIC_RELAXED, __HIP_MEMORY_SCOPE_AGENT) < tgt)
        __builtin_amdgcn_s_sleep(4);
    }
  }
  __syncthreads();
}

// ---------------- precompute ----------------
__global__ void k_pre(
  const float* __restrict__ strokes, const int* __restrict__ chars, const float* __restrict__ cmask,
  const float* __restrict__ emb,
  const float* __restrict__ Wih1, const float* __restrict__ Whh2, const float* __restrict__ Wo,
  const float* __restrict__ bih0, const float* __restrict__ bhh0,
  const float* __restrict__ bih1, const float* __restrict__ bhh1,
  const float* __restrict__ bih2, const float* __restrict__ bhh2,
  const float* __restrict__ bo,
  const float* __restrict__ h0, const float* __restrict__ c0,
  const float* __restrict__ w0, const float* __restrict__ k0,
  float* __restrict__ ws)
{
  const int gid = blockIdx.x*blockDim.x + threadIdx.x;
  const int gsz = gridDim.x*blockDim.x;
  float* ctxp = ws + OF_CTX;
  for (int i = gid; i < 64*64*128; i += gsz) {
    int b = i >> 13, rem = i & 8191, u = rem >> 7, e = rem & 127;
    ctxp[i] = emb[chars[b*64+u]*128+e] * cmask[b*64+u];
  }
  float* xT = ws + OF_XT;
  for (int i = gid; i < T_*3*64; i += gsz) {
    int t = i/192, r = i - t*192, j = r >> 6, b = r & 63;
    xT[i] = strokes[(b*T_+t)*3+j];
  }
  const float* h2c = h0 + 800;
  float* b0 = ws + OF_B0; float* b1 = ws + OF_B1; float* b2 = ws + OF_B2;
  for (int r = gid; r < 1600; r += gsz) {
    b0[r] = bih0[r] + bhh0[r];
    float s1 = bih1[r] + bhh1[r];
    const float* w1 = Wih1 + (size_t)r*531 + 131;
    for (int j = 0; j < 400; ++j) s1 += w1[j]*h2c[j];
    b1[r] = s1;
    float s2 = bih2[r] + bhh2[r];
    const float* w2 = Whh2 + (size_t)r*400;
    for (int j = 0; j < 400; ++j) s2 += w2[j]*h2c[j];
    b2[r] = s2;
  }
  float* ob = ws + OF_OB;
  for (int r = gid; r < 121; r += gsz) {
    float s = bo[r];
    const float* wr = Wo + (size_t)r*1200 + 800;
    for (int j = 0; j < 400; ++j) s += wr[j]*h2c[j];
    ob[r] = s;
  }
  float* wS = ws + OF_WS2;
  for (int i = gid; i < 8192; i += gsz) wS[i] = w0[i & 127];
  float* kS = ws + OF_KS;
  for (int i = gid; i < 640; i += gsz) kS[i] = k0[i % 10];
  float* n1hp = ws + OF_N1H; float* n1cp = ws + OF_N1C;
  for (int i = gid; i < 25600; i += gsz) {
    n1hp[i] = h0[400 + (i % 400)];   // [b][j]
    n1cp[i] = c0[400 + (i >> 6)];    // [n][b]
  }
}

// ---------------- hA_0 = LSTM0(x_0, w0 | h0[0], c0[0]) ----------------
__global__ __launch_bounds__(512) void k_init(
  const float* __restrict__ Wih0, const float* __restrict__ Whh0,
  const float* __restrict__ h0, const float* __restrict__ c0, const float* __restrict__ w0,
  float* __restrict__ ws)
{
  const int lane = threadIdx.x & 63;
  const int wv = threadIdx.x >> 6;
  const int n = blockIdx.x*8 + wv;   // 50 blocks * 8 waves = 400
  if (n >= 400) return;
  const float* bias0 = ws + OF_B0;
  const float* xT = ws + OF_XT;
  float* hA = ws + OF_HA;
  float g[4];
  #pragma unroll
  for (int q = 0; q < 4; ++q) {
    int r = q*400 + n;
    const float* wi = Wih0 + (size_t)r*131;
    const float* wh = Whh0 + (size_t)r*400;
    float a = bias0[r];
    a += xT[0*64+lane]*wi[0] + xT[1*64+lane]*wi[1] + xT[2*64+lane]*wi[2];
    for (int e = 0; e < 128; ++e) a += w0[e]*wi[3+e];
    for (int j = 0; j < 400; ++j) a += h0[j]*wh[j];
    g[q] = a;
  }
  float cn = sigf(g[1])*c0[n] + sigf(g[0])*tanhf(g[2]);
  hA[lane*400 + n] = sigf(g[3])*tanhf(cn);
}

// ---------------- gate GEMV: wave = (K-quarter, row-half), lane = batch ------
// virtual K = [x(3) | w(128) | h(400)]; kq0: x+w, kq1..3: h thirds.
__device__ __forceinline__ void gemv8(
    int xt_idx, int lane, int kq, int rh, int ns, int ch,
    const float* __restrict__ bias,
    const float* __restrict__ Wxw, int sxw,
    const float* __restrict__ Whh, int shh, int hoff,
    const float* __restrict__ xT,
    const float* hLs, const float* wLs, float* pLs)
{
  const int hrows = 2*ch;            // rows per wave (half of 4*ch)
  float acc[8]; const float* wrow[8];
  #pragma unroll
  for (int s = 0; s < 8; ++s) {
    if (s < hrows) {
      int rr = rh*hrows + s;
      int q = rr / ch, nl = rr - q*ch;
      int r = __builtin_amdgcn_readfirstlane(q*H_ + ns + nl);
      if (kq == 0) { wrow[s] = Wxw + (size_t)r*sxw;        acc[s] = bias[r]; }
      else         { wrow[s] = Whh + (size_t)r*shh + hoff; acc[s] = 0.f; }
    }
  }
  if (kq == 0) {
    float x0 = xT[(xt_idx*3+0)*64+lane];
    float x1 = xT[(xt_idx*3+1)*64+lane];
    float x2 = xT[(xt_idx*3+2)*64+lane];
    #pragma unroll
    for (int s = 0; s < 8; ++s) if (s < hrows)
      acc[s] += x0*wrow[s][0] + x1*wrow[s][1] + x2*wrow[s][2];
    #pragma unroll 2
    for (int ec = 0; ec < 32; ++ec) {
      float4 w4 = *(const float4*)&wLs[lane*132 + ec*4];
      #pragma unroll
      for (int s = 0; s < 8; ++s) if (s < hrows) {
        const float* wp = wrow[s] + 3 + ec*4;
        acc[s] += w4.x*wp[0] + w4.y*wp[1] + w4.z*wp[2] + w4.w*wp[3];
      }
    }
  } else {
    int jb = (kq==1) ? 0 : (kq==2 ? 33 : 66);
    int je = (kq==1) ? 33 : (kq==2 ? 66 : 100);
    #pragma unroll 2
    for (int jc = jb; jc < je; ++jc) {
      float4 hv = *(const float4*)&hLs[lane*404 + jc*4];
      #pragma unroll
      for (int s = 0; s < 8; ++s) if (s < hrows) {
        const float* wp = wrow[s] + jc*4;
        acc[s] += hv.x*wp[0] + hv.y*wp[1] + hv.z*wp[2] + hv.w*wp[3];
      }
    }
  }
  #pragma unroll
  for (int s = 0; s < 8; ++s) if (s < hrows)
    pLs[((rh*4+kq)*8 + s)*64 + lane] = acc[s];
}

// ---------------- persistent scan ----------------
__global__ __launch_bounds__(NTHR) void k_scan(
  const float* __restrict__ Wih0, const float* __restrict__ Whh0,
  const float* __restrict__ Wih1, const float* __restrict__ Whh1,
  const float* __restrict__ Wih2,
  const float* __restrict__ Wa, const float* __restrict__ ba,
  const float* __restrict__ c0, float* __restrict__ ws)
{
  __shared__ __align__(16) float hLs[64*404];   // h state [b][404]
  __shared__ __align__(16) float wLs[64*132];   // w state [b][132]
  __shared__ float pLs[8*8*64];                 // partials [wave][slot][lane]
  __shared__ float hab[400];
  __shared__ float aScr[32];
  __shared__ float phL[64];

  const int tid = threadIdx.x;
  const int lane = tid & 63;
  const int wv = __builtin_amdgcn_readfirstlane(tid >> 6);
  const int kq = wv & 3, rh = wv >> 2;
  const int bid = blockIdx.x;
  const int ns = bid*4;              // 4 hidden units per block, exact

  unsigned* ctrl = (unsigned*)ws;
  unsigned* cnt = &ctrl[0];
  unsigned* gen = &ctrl[32];
  float* wS  = ws + OF_WS2;
  float* kS  = ws + OF_KS;
  float* n0h = ws + OF_N0H; float* n0c = ws + OF_N0C;
  float* n1h = ws + OF_N1H; float* n1c = ws + OF_N1C;
  float* hA  = ws + OF_HA;
  const float* bias0 = ws + OF_B0;
  const float* bias1 = ws + OF_B1;
  const float* bias2 = ws + OF_B2;
  const float* xT  = ws + OF_XT;
  const float* ctx = ws + OF_CTX;
  __hip_bfloat16* a0 = (__hip_bfloat16*)(ws + OF_A0);
  __hip_bfloat16* a1 = (__hip_bfloat16*)(ws + OF_A1);

  unsigned bgen = 0;

  for (int t = 0; t < T_; ++t) {
    // ===== phase A: single-wave attention (blocks 0..63) ∥ prestage n1h =====
    if (bid < 64) {
      if (wv == 0) {
        const int b = bid;
        for (int i = lane; i < 200; i += 64) {        // stage hA[b] -> LDS
          float2 v = ld_dev2(&hA[b*400 + i*2]);
          *(float2*)&hab[i*2] = v;
        }
        asm volatile("s_waitcnt vmcnt(0) lgkmcnt(0)" ::: "memory");
        float s = 0.f;
        if (lane < 30) {                              // p-rows, lane = row
          const float* wr = Wa + lane*400;
          #pragma unroll 4
          for (int j = 0; j < 400; ++j) s += hab[j]*wr[j];
          s += ba[lane];
        }
        float p = expf(s);
        float val = p;
        if (lane >= 20 && lane < 30) {                // kappa += k_prev
          float kap = p + kS[b*10 + (lane-20)];
          kS[b*10 + (lane-20)] = kap;
          val = kap;
        }
        if (lane < 30) aScr[lane] = val;
        asm volatile("s_waitcnt lgkmcnt(0)" ::: "memory");
        float uu = (float)lane, ph = 0.f;             // phi, lane = u
        #pragma unroll
        for (int m = 0; m < 10; ++m) {
          float d = aScr[20+m] - uu;
          ph += aScr[m] * expf(-aScr[10+m]*d*d);
        }
        phL[lane] = ph;
        asm volatile("s_waitcnt lgkmcnt(0)" ::: "memory");
        float a0w = 0.f, a1w = 0.f;                   // w = phi @ ctx[b]
        const float* cb = ctx + (size_t)b*8192;
        for (int u2 = 0; u2 < 64; ++u2) {
          float phv = phL[u2];
          a0w += phv * cb[u2*128 + lane];
          a1w += phv * cb[u2*128 + 64 + lane];
        }
        st_dev(&wS[b*128 + lane], a0w);
        st_dev(&wS[b*128 + 64 + lane], a1w);
      } else {
        for (int i = tid - 64; i < 12800; i += (NTHR-64)) {
          int b2 = i/200, jc = i - b2*200;
          float2 v = ld_dev2(&n1h[b2*400 + jc*2]);
          *(float2*)&hLs[b2*404 + jc*2] = v;
        }
      }
    } else {
      for (int i = tid; i < 12800; i += NTHR) {
        int b2 = i/200, jc = i - b2*200;
        float2 v = ld_dev2(&n1h[b2*400 + jc*2]);
        *(float2*)&hLs[b2*404 + jc*2] = v;
      }
    }
    gbar(cnt, gen, ++bgen);

    // ================= phase B: LSTM1 =================
    for (int i = tid; i < 4096; i += NTHR) {           // stage w_t
      int b2 = i >> 6, ec = i & 63;
      float2 v = ld_dev2(&wS[b2*128 + ec*2]);
      *(float2*)&wLs[b2*132 + ec*2] = v;
    }
    __syncthreads();
    gemv8(t, lane, kq, rh, ns, 4, bias1, Wih1, 531, Whh1, 400, 0, xT, hLs, wLs, pLs);
    __syncthreads();
    for (int i = tid; i < 256; i += NTHR) {
      int nl = i >> 6, b = i & 63, n = ns+nl;
      float g[4];
      #pragma unroll
      for (int q = 0; q < 4; ++q) {
        int rr = q*4+nl; int r2 = (rr >= 8); int s = rr - r2*8;
        float v = 0.f;
        #pragma unroll
        for (int k2 = 0; k2 < 4; ++k2) v += pLs[((r2*4+k2)*8+s)*64+b];
        g[q] = v;
      }
      float cp = n1c[n*64+b];
      float cn = sigf(g[1])*cp + sigf(g[0])*tanhf(g[2]);
      float hn = sigf(g[3])*tanhf(cn);
      n0c[n*64+b] = cn;                                // private
      st_dev(&n0h[b*400+n], hn);                       // cross-block
      a0[((size_t)t*64+b)*400+n] = __float2bfloat16(hn);
    }
    gbar(cnt, gen, ++bgen);

    // ========== phase C: LSTM2, then LSTM0_{t+1} (both use n0h, w_t) ========
    for (int i = tid; i < 12800; i += NTHR) {          // stage n0h (new)
      int b2 = i/200, jc = i - b2*200;
      float2 v = ld_dev2(&n0h[b2*400 + jc*2]);
      *(float2*)&hLs[b2*404 + jc*2] = v;
    }
    __syncthreads();                                   // wLs still holds w_t
    gemv8(t, lane, kq, rh, ns, 4, bias2, Wih2, 531, Wih2, 531, 131, xT, hLs, wLs, pLs);
    __syncthreads();
    for (int i = tid; i < 256; i += NTHR) {
      int nl = i >> 6, b = i & 63, n = ns+nl;
      float g[4];
      #pragma unroll
      for (int q = 0; q < 4; ++q) {
        int rr = q*4+nl; int r2 = (rr >= 8); int s = rr - r2*8;
        float v = 0.f;
        #pragma unroll
        for (int k2 = 0; k2 < 4; ++k2) v += pLs[((r2*4+k2)*8+s)*64+b];
        g[q] = v;
      }
      float cn = sigf(g[1])*c0[800+n] + sigf(g[0])*tanhf(g[2]);
      float hn = sigf(g[3])*tanhf(cn);
      n1c[n*64+b] = cn;                                // private
      st_dev(&n1h[b*400+n], hn);                       // cross-block
      a1[((size_t)t*64+b)*400+n] = __float2bfloat16(hn);
    }
    __syncthreads();                                   // pLs reuse guard
    if (t < T_-1) {
      gemv8(t+1, lane, kq, rh, ns, 4, bias0, Wih0, 131, Whh0, 400, 0, xT, hLs, wLs, pLs);
      __syncthreads();
      for (int i = tid; i < 256; i += NTHR) {
        int nl = i >> 6, b = i & 63, n = ns+nl;
        float g[4];
        #pragma unroll
        for (int q = 0; q < 4; ++q) {
          int rr = q*4+nl; int r2 = (rr >= 8); int s = rr - r2*8;
          float v = 0.f;
          #pragma unroll
          for (int k2 = 0; k2 < 4; ++k2) v += pLs[((r2*4+k2)*8+s)*64+b];
          g[q] = v;
        }
        float cp = n0c[n*64+b];                        // private
        float cn = sigf(g[1])*cp + sigf(g[0])*tanhf(g[2]);
        st_dev(&hA[b*400+n], sigf(g[3])*tanhf(cn));    // hA_{t+1}, cross-block
      }
    }
    gbar(cnt, gen, ++bgen);
  }
}

// ---------------- output projection + MDN/eos loss ----------------
__global__ __launch_bounds__(NTHR) void k_outloss(
  const float* __restrict__ Wo, const float* __restrict__ strokes, float* __restrict__ ws)
{
  __shared__ __align__(16) float hL4[64*404];
  __shared__ float oL[121*65];
  const int t = blockIdx.x;
  const int tid = threadIdx.x;
  const int lane = tid & 63;
  const int wv = __builtin_amdgcn_readfirstlane(tid >> 6);
  const float* ob = ws + OF_OB;
  const __hip_bfloat16* a0 = (const __hip_bfloat16*)(ws + OF_A0);
  const __hip_bfloat16* a1 = (const __hip_bfloat16*)(ws + OF_A1);

  float acc[16];
  #pragma unroll
  for (int s = 0; s < 16; ++s) { int r = wv + 8*s; acc[s] = (r < 121) ? ob[r] : 0.f; }

  const unsigned* src0 = (const unsigned*)(a0 + (size_t)t*25600);
  for (int i = tid; i < 12800; i += NTHR) {
    unsigned v = src0[i];
    int b = i/200, jc = i - b*200;
    hL4[b*404+jc*2+0] = __uint_as_float(v << 16);
    hL4[b*404+jc*2+1] = __uint_as_float(v & 0xffff0000u);
  }
  __syncthreads();
  for (int jc = 0; jc < 100; ++jc) {
    float4 hv = *(const float4*)&hL4[lane*404+jc*4];
    #pragma unroll
    for (int s = 0; s < 16; ++s) {
      int r = wv + 8*s;
      if (r < 121) {
        const float* wp = Wo + (size_t)r*1200 + jc*4;
        acc[s] += hv.x*wp[0] + hv.y*wp[1] + hv.z*wp[2] + hv.w*wp[3];
      }
    }
  }
  __syncthreads();
  const unsigned* src1 = (const unsigned*)(a1 + (size_t)t*25600);
  for (int i = tid; i < 12800; i += NTHR) {
    unsigned v = src1[i];
    int b = i/200, jc = i - b*200;
    hL4[b*404+jc*2+0] = __uint_as_float(v << 16);
    hL4[b*404+jc*2+1] = __uint_as_float(v & 0xffff0000u);
  }
  __syncthreads();
  for (int jc = 0; jc < 100; ++jc) {
    float4 hv = *(const float4*)&hL4[lane*404+jc*4];
    #pragma unroll
    for (int s = 0; s < 16; ++s) {
      int r = wv + 8*s;
      if (r < 121) {
        const float* wp = Wo + (size_t)r*1200 + 400 + jc*4;
        acc[s] += hv.x*wp[0] + hv.y*wp[1] + hv.z*wp[2] + hv.w*wp[3];
      }
    }
  }
  #pragma unroll
  for (int s = 0; s < 16; ++s) { int r = wv + 8*s; if (r < 121) oL[r*65+lane] = acc[s]; }
  __syncthreads();

  if (wv == 0) {
    const int b = lane;
    float x0 = strokes[(b*T_+t)*3+0];
    float x1 = strokes[(b*T_+t)*3+1];
    float y  = strokes[(b*T_+t)*3+2];
    float mp = -1e30f;
    #pragma unroll
    for (int k = 0; k < 20; ++k) mp = fmaxf(mp, oL[(80+k)*65+b]);
    float sp = 0.f;
    #pragma unroll
    for (int k = 0; k < 20; ++k) sp += expf(oL[(80+k)*65+b] - mp);
    float lsep = mp + logf(sp);
    float sk[20]; float ms = -1e30f;
    #pragma unroll
    for (int k = 0; k < 20; ++k) {
      float mu0 = oL[(2*k)*65+b],    mu1 = oL[(2*k+1)*65+b];
      float l0  = oL[(40+2*k)*65+b], l1  = oL[(41+2*k)*65+b];
      float rho = tanhf(oL[(100+k)*65+b]);
      float t0 = (x0-mu0)*expf(-l0);
      float t1 = (x1-mu1)*expf(-l1);
      float on = 1.f - rho*rho;
      float Z = t0*t0 + t1*t1 - 2.f*rho*t0*t1;
      float logN = -Z/(2.f*on) - (1.8378770664093453f + l0 + l1 + 0.5f*logf(on));
      float sv = (oL[(80+k)*65+b] - lsep) + logN;
      sk[k] = sv; ms = fmaxf(ms, sv);
    }
    float ss = 0.f;
    #pragma unroll
    for (int k = 0; k < 20; ++k) ss += expf(sk[k]-ms);
    float stroke = -(ms + logf(ss));
    float z = oL[120*65+b];
    float eos = fmaxf(z,0.f) - z*y + log1pf(expf(-fabsf(z)));
    #pragma unroll
    for (int off = 32; off > 0; off >>= 1) {
      stroke += __shfl_down(stroke, off, 64);
      eos    += __shfl_down(eos, off, 64);
    }
    if (lane == 0) { atomicAdd(ws+64, stroke); atomicAdd(ws+65, eos); }
  }
}

__global__ void k_fin(const float* __restrict__ ws, float* __restrict__ out) {
  if (threadIdx.x == 0) {
    out[0] = ws[64] * (1.f/25600.f);
    out[1] = ws[65] * (1.f/25600.f);
  }
}

// ---------------- host ----------------
extern "C" void kernel_launch(void* const* d_in, const int* in_sizes, int n_in,
                              void* d_out, int out_size, void* d_ws, size_t ws_size,
                              hipStream_t stream) {
  const float* strokes = (const float*)d_in[0];
  const int*   chars   = (const int*)d_in[1];
  const float* cmask   = (const float*)d_in[2];
  const float* emb     = (const float*)d_in[3];
  const float* Wih0    = (const float*)d_in[4];
  const float* Whh0    = (const float*)d_in[5];
  const float* bih0    = (const float*)d_in[6];
  const float* bhh0    = (const float*)d_in[7];
  const float* Wih1    = (const float*)d_in[8];
  const float* Whh1    = (const float*)d_in[9];
  const float* bih1    = (const float*)d_in[10];
  const float* bhh1    = (const float*)d_in[11];
  const float* Wih2    = (const float*)d_in[12];
  const float* Whh2    = (const float*)d_in[13];
  const float* bih2    = (const float*)d_in[14];
  const float* bhh2    = (const float*)d_in[15];
  const float* Wa      = (const float*)d_in[16];
  const float* ba      = (const float*)d_in[17];
  const float* Wo      = (const float*)d_in[18];
  const float* bo      = (const float*)d_in[19];
  const float* h0      = (const float*)d_in[20];
  const float* c0      = (const float*)d_in[21];
  const float* w0      = (const float*)d_in[22];
  const float* k0      = (const float*)d_in[23];
  float* ws = (float*)d_ws;
  float* out = (float*)d_out;
  if (ws_size < WS_FLOATS*sizeof(float)) return;  // ~44 MB required

  hipMemsetAsync(d_ws, 0, 512, stream);  // control words + loss accumulators
  k_pre<<<256, 256, 0, stream>>>(strokes, chars, cmask, emb, Wih1, Whh2, Wo,
                                 bih0, bhh0, bih1, bhh1, bih2, bhh2, bo,
                                 h0, c0, w0, k0, ws);
  k_init<<<50, 512, 0, stream>>>(Wih0, Whh0, h0, c0, w0, ws);
  k_scan<<<NBLK, NTHR, 0, stream>>>(Wih0, Whh0, Wih1, Whh1, Wih2, Wa, ba, c0, ws);
  k_outloss<<<T_, NTHR, 0, stream>>>(Wo, strokes, ws);
  k_fin<<<1, 64, 0, stream>>>(ws, out);
}

// Round 6
// 37394.128 us; speedup vs baseline: 1.1057x; 1.1057x over previous
//
#include <hip/hip_runtime.h>
#include <hip/hip_bf16.h>

// ============================================================================
// Seq2Seq (Graves handwriting) forward on MI355X — Round 5 (= Round 3 kernel,
// resubmitted; Rounds 4-5 benches failed with GPUAcquisitionTimeout, so this
// design remains unmeasured).
// Persistent scan, 100 blocks x 512 thr (1 block/CU via LDS).
// 2 store-based global barriers + 1 attention flag per step.
// Cross-block state via wide sc0sc1 (coherent, cache-bypassing) dwordx4
// loads/stores, batched-issue. No wbl2/inv, no RMW contention:
// weights/ctx stay L2-resident. x+w gate parts precomputed into registers
// carried across the barrier; attention overlapped with LSTM1 h-part.
// ============================================================================

typedef float f4 __attribute__((ext_vector_type(4)));

#define B_ 64
#define T_ 400
#define H_ 400
#define NBLK 100
#define NTHR 512
#define FLW 32   // words per flag line (128B)

// ---------------- ws layout (float units) ----------------
// ctrl words [0..8191]: gen@0, barrier flags @FLW*(1+bid), attn flags
// @FLW*(101+b), loss @5312/5313. memset 32KB covers all.
constexpr size_t OF_LOSS = 5312;
constexpr size_t OF_WS2  = 8192;                  // w state [64][128]      (coh)
constexpr size_t OF_KS   = OF_WS2 + 8192;         // kappa [64][10]         (priv)
constexpr size_t OF_N0H  = OF_KS + 640;           // n0h [b][400]           (coh)
constexpr size_t OF_N0C  = OF_N0H + 25600;        // n0c [n][64]            (priv)
constexpr size_t OF_N1H  = OF_N0C + 25600;        // n1h [b][400]           (coh)
constexpr size_t OF_N1C  = OF_N1H + 25600;        // n1c [n][64]            (priv)
constexpr size_t OF_HA   = OF_N1C + 25600;        // hA  [b][400]           (coh)
constexpr size_t OF_B0   = OF_HA + 25600;         // bias0 [1600]
constexpr size_t OF_B1   = OF_B0 + 1600;          // bias1 + h2c@Wih1[:,131:531]
constexpr size_t OF_B2   = OF_B1 + 1600;          // bias2 + h2c@Whh2
constexpr size_t OF_OB   = OF_B2 + 1600;          // obias [121] (+pad)
constexpr size_t OF_XT   = OF_OB + 128;           // xT [t][3][64]
constexpr size_t OF_CTX  = OF_XT + (size_t)T_*3*64;     // ctx [b][u][e]
constexpr size_t OF_A0   = OF_CTX + (size_t)64*64*128;  // bf16 n0h_all
constexpr size_t OF_A1   = OF_A0 + (size_t)T_*64*400/2; // bf16 n1h_all
constexpr size_t WS_FLOATS = OF_A1 + (size_t)T_*64*400/2;

__device__ __forceinline__ float sigf(float x) { return 1.f/(1.f + expf(-x)); }

// ---------------- coherent (sc0 sc1) wide access ----------------
__device__ __forceinline__ void ldg4(f4& d, const float* p) {
  asm volatile("global_load_dwordx4 %0, %1, off sc0 sc1" : "=v"(d) : "v"(p));
}
__device__ __forceinline__ void stg4(float* p, f4 v) {
  asm volatile("global_store_dwordx4 %0, %1, off sc0 sc1" :: "v"(p), "v"(v) : "memory");
}
__device__ __forceinline__ void stg1(float* p, float v) {
  asm volatile("global_store_dword %0, %1, off sc0 sc1" :: "v"(p), "v"(v) : "memory");
}
__device__ __forceinline__ void waitv0() {
  asm volatile("s_waitcnt vmcnt(0)" ::: "memory");
  __builtin_amdgcn_sched_barrier(0);
}
__device__ __forceinline__ unsigned ldf(const unsigned* p) {
  return __hip_atomic_load(p, __ATOMIC_RELAXED, __HIP_MEMORY_SCOPE_AGENT);
}
__device__ __forceinline__ void stf(unsigned* p, unsigned v) {
  __hip_atomic_store(p, v, __ATOMIC_RELAXED, __HIP_MEMORY_SCOPE_AGENT);
}

// batched coherent stage: [64][400] global -> [64][404] LDS (6400 f4 units)
__device__ __forceinline__ void stage_h(const float* __restrict__ g, float* lds, int tid) {
  f4 v[13];
  const float* pa[13];
  #pragma unroll
  for (int k = 0; k < 13; ++k) {
    int u = tid + k*512;
    int uu = (u < 6400) ? u : 6399;
    int b = uu/100, jc = uu - b*100;
    pa[k] = g + b*400 + jc*4;
  }
  #pragma unroll
  for (int k = 0; k < 13; ++k) ldg4(v[k], pa[k]);
  waitv0();
  #pragma unroll
  for (int k = 0; k < 13; ++k) {
    int u = tid + k*512;
    if (u < 6400) { int b = u/100, jc = u - b*100; *(f4*)&lds[b*404 + jc*4] = v[k]; }
  }
}

// ---------------- store-based global barrier (no fences, no RMW) ----------
__device__ __forceinline__ void gbar(unsigned* ctrl, int bid, unsigned tgt,
                                     int tid, int lane, int wv) {
  __syncthreads();
  if (tid == 0) {
    asm volatile("s_waitcnt vmcnt(0)" ::: "memory");   // publish stores acked
    stf(&ctrl[FLW*(1+bid)], tgt);
  }
  if (bid == 0) {
    if (wv == 0) {
      bool on = (lane < 50);
      const unsigned* f0 = &ctrl[FLW*(1+2*lane)];
      const unsigned* f1 = &ctrl[FLW*(2+2*lane)];
      for (;;) {
        unsigned a = on ? ldf(f0) : tgt;
        unsigned b = on ? ldf(f1) : tgt;
        if (__all((int)(a >= tgt && b >= tgt))) break;
        __builtin_amdgcn_s_sleep(1);
      }
      if (lane == 0) stf(&ctrl[0], tgt);
    }
  } else if (tid == 0) {
    while (ldf(&ctrl[0]) < tgt) __builtin_amdgcn_s_sleep(1);
  }
  __syncthreads();
}

__device__ __forceinline__ unsigned bfu(float x) {
  union { __hip_bfloat16 h; unsigned short u; } c;
  c.h = __float2bfloat16(x);
  return (unsigned)c.u;
}

// ---------------- precompute ----------------
__global__ void k_pre(
  const float* __restrict__ strokes, const int* __restrict__ chars, const float* __restrict__ cmask,
  const float* __restrict__ emb,
  const float* __restrict__ Wih1, const float* __restrict__ Whh2, const float* __restrict__ Wo,
  const float* __restrict__ bih0, const float* __restrict__ bhh0,
  const float* __restrict__ bih1, const float* __restrict__ bhh1,
  const float* __restrict__ bih2, const float* __restrict__ bhh2,
  const float* __restrict__ bo,
  const float* __restrict__ h0, const float* __restrict__ c0,
  const float* __restrict__ w0, const float* __restrict__ k0,
  float* __restrict__ ws)
{
  const int gid = blockIdx.x*blockDim.x + threadIdx.x;
  const int gsz = gridDim.x*blockDim.x;
  float* ctxp = ws + OF_CTX;
  for (int i = gid; i < 64*64*128; i += gsz) {
    int b = i >> 13, rem = i & 8191, u = rem >> 7, e = rem & 127;
    ctxp[i] = emb[chars[b*64+u]*128+e] * cmask[b*64+u];
  }
  float* xT = ws + OF_XT;
  for (int i = gid; i < T_*3*64; i += gsz) {
    int t = i/192, r = i - t*192, j = r >> 6, b = r & 63;
    xT[i] = strokes[(b*T_+t)*3+j];
  }
  const float* h2c = h0 + 800;
  float* b0 = ws + OF_B0; float* b1 = ws + OF_B1; float* b2 = ws + OF_B2;
  for (int r = gid; r < 1600; r += gsz) {
    b0[r] = bih0[r] + bhh0[r];
    float s1 = bih1[r] + bhh1[r];
    const float* w1 = Wih1 + (size_t)r*531 + 131;
    for (int j = 0; j < 400; ++j) s1 += w1[j]*h2c[j];
    b1[r] = s1;
    float s2 = bih2[r] + bhh2[r];
    const float* w2 = Whh2 + (size_t)r*400;
    for (int j = 0; j < 400; ++j) s2 += w2[j]*h2c[j];
    b2[r] = s2;
  }
  float* ob = ws + OF_OB;
  for (int r = gid; r < 121; r += gsz) {
    float s = bo[r];
    const float* wr = Wo + (size_t)r*1200 + 800;
    for (int j = 0; j < 400; ++j) s += wr[j]*h2c[j];
    ob[r] = s;
  }
  float* kS = ws + OF_KS;
  for (int i = gid; i < 640; i += gsz) kS[i] = k0[i % 10];
  float* n1hp = ws + OF_N1H; float* n1cp = ws + OF_N1C;
  for (int i = gid; i < 25600; i += gsz) {
    n1hp[i] = h0[400 + (i % 400)];   // [b][j]
    n1cp[i] = c0[400 + (i >> 6)];    // [n][b]
  }
}

// ---------------- hA_0 = LSTM0(x_0, w0 | h0[0], c0[0]) ----------------
__global__ __launch_bounds__(512) void k_init(
  const float* __restrict__ Wih0, const float* __restrict__ Whh0,
  const float* __restrict__ h0, const float* __restrict__ c0, const float* __restrict__ w0,
  float* __restrict__ ws)
{
  const int lane = threadIdx.x & 63;
  const int wv = threadIdx.x >> 6;
  const int n = blockIdx.x*8 + wv;   // 50 blocks * 8 waves = 400
  if (n >= 400) return;
  const float* bias0 = ws + OF_B0;
  const float* xT = ws + OF_XT;
  float* hA = ws + OF_HA;
  float g[4];
  #pragma unroll
  for (int q = 0; q < 4; ++q) {
    int r = q*400 + n;
    const float* wi = Wih0 + (size_t)r*131;
    const float* wh = Whh0 + (size_t)r*400;
    float a = bias0[r];
    a += xT[0*64+lane]*wi[0] + xT[1*64+lane]*wi[1] + xT[2*64+lane]*wi[2];
    for (int e = 0; e < 128; ++e) a += w0[e]*wi[3+e];
    for (int j = 0; j < 400; ++j) a += h0[j]*wh[j];
    g[q] = a;
  }
  float cn = sigf(g[1])*c0[n] + sigf(g[0])*tanhf(g[2]);
  hA[lane*400 + n] = sigf(g[3])*tanhf(cn);
}

// ---------------- persistent scan ----------------
__global__ __launch_bounds__(NTHR, 2) void k_scan(
  const float* __restrict__ Wih0, const float* __restrict__ Whh0,
  const float* __restrict__ Wih1, const float* __restrict__ Whh1,
  const float* __restrict__ Wih2,
  const float* __restrict__ Wa, const float* __restrict__ ba,
  const float* __restrict__ c0, float* __restrict__ ws)
{
  __shared__ __align__(16) float hLs[64*404];   // h state [b][404]
  __shared__ __align__(16) float wLs[64*132];   // w state [b][132]
  __shared__ float pLs[8*8*64];                 // partials [slot8][s8][lane]
  __shared__ __align__(16) float hab[400];
  __shared__ float aScr[32];
  __shared__ float phL[64];

  const int tid  = threadIdx.x;
  const int lane = tid & 63;
  const int wv   = __builtin_amdgcn_readfirstlane(tid >> 6);
  const int kq   = wv & 3, rh = wv >> 2;     // A-mapping (L1)
  const int rh2  = wv & 1, kc = wv >> 1;     // C-mapping (L2/L0)
  const int bid  = blockIdx.x;
  const int ns   = bid*4;                    // 4 hidden units per block
  const bool isAttn = (bid < 64);

  unsigned* ctrl = (unsigned*)ws;
  float* wS  = ws + OF_WS2;
  float* kS  = ws + OF_KS;
  float* n0h = ws + OF_N0H; float* n0c = ws + OF_N0C;
  float* n1h = ws + OF_N1H; float* n1c = ws + OF_N1C;
  float* hA  = ws + OF_HA;
  const float* bias0 = ws + OF_B0;
  const float* bias1 = ws + OF_B1;
  const float* bias2 = ws + OF_B2;
  const float* c2c = c0 + 800;
  const float* xT  = ws + OF_XT;
  const float* ctx = ws + OF_CTX;
  unsigned short* a0 = (unsigned short*)(ws + OF_A0);
  unsigned short* a1 = (unsigned short*)(ws + OF_A1);

  float acc1[8], acc2[8], acc0[8];
  unsigned tgt = 0;

  for (int t = 0; t < T_; ++t) {
    // =================== phase A ===================
    stage_h(n1h, hLs, tid);                  // LSTM1 h-state -> LDS
    __syncthreads();

    // ---- attention (blocks 0..63, wave 0 only) ----
    if (isAttn && wv == 0) {
      const int b = bid;
      f4 v0, v1;
      const float* p0 = &hA[b*400 + lane*4];
      bool on1 = (lane < 36);
      const float* p1 = on1 ? &hA[b*400 + 256 + lane*4] : p0;
      ldg4(v0, p0); ldg4(v1, p1);
      waitv0();
      *(f4*)&hab[lane*4] = v0;
      if (on1) *(f4*)&hab[256 + lane*4] = v1;
      asm volatile("s_waitcnt lgkmcnt(0)" ::: "memory");
      float s = 0.f;
      if (lane < 30) {
        const float* wr = Wa + lane*400;
        #pragma unroll 4
        for (int j = 0; j < 400; ++j) s += hab[j]*wr[j];
        s += ba[lane];
      }
      float p = expf(s);
      float val = p;
      if (lane >= 20 && lane < 30) {
        float kap = p + kS[b*10 + (lane-20)];
        kS[b*10 + (lane-20)] = kap;
        val = kap;
      }
      if (lane < 30) aScr[lane] = val;
      asm volatile("s_waitcnt lgkmcnt(0)" ::: "memory");
      float uu = (float)lane, ph = 0.f;
      #pragma unroll
      for (int m = 0; m < 10; ++m) {
        float d = aScr[20+m] - uu;
        ph += aScr[m] * expf(-aScr[10+m]*d*d);
      }
      phL[lane] = ph;
      asm volatile("s_waitcnt lgkmcnt(0)" ::: "memory");
      float a0w = 0.f, a1w = 0.f;
      const float* cb = ctx + (size_t)b*8192;
      for (int u2 = 0; u2 < 64; ++u2) {
        float phv = phL[u2];
        a0w += phv * cb[u2*128 + lane];
        a1w += phv * cb[u2*128 + 64 + lane];
      }
      stg1(&wS[b*128 + lane], a0w);
      stg1(&wS[b*128 + 64 + lane], a1w);
      asm volatile("s_waitcnt vmcnt(0)" ::: "memory");
      if (lane == 0) stf(&ctrl[FLW*(101+b)], (unsigned)(t+1));
    }

    // ---- LSTM1 h-part (waves kq=1..3; 75% of the GEMV) ----
    #pragma unroll
    for (int s = 0; s < 8; ++s) acc1[s] = 0.f;
    if (kq != 0) {
      const float* wr[8];
      #pragma unroll
      for (int s = 0; s < 8; ++s) {
        int rr = rh*8+s;
        int r = __builtin_amdgcn_readfirstlane((rr>>2)*H_ + ns + (rr&3));
        wr[s] = Whh1 + (size_t)r*400;
      }
      int jb = (kq==1)?0:(kq==2?33:66);
      int je = (kq==1)?33:(kq==2?66:100);
      for (int jc = jb; jc < je; ++jc) {
        f4 hv = *(const f4*)&hLs[lane*404 + jc*4];
        #pragma unroll
        for (int s = 0; s < 8; ++s) {
          const float* wp = wr[s] + jc*4;
          acc1[s] += hv.x*wp[0] + hv.y*wp[1] + hv.z*wp[2] + hv.w*wp[3];
        }
      }
    }
    __syncthreads();

    // ---- wait for all attention flags (wave 0, lane-parallel) ----
    if (wv == 0) {
      const unsigned* af = &ctrl[FLW*(101+lane)];
      while (!__all((int)(ldf(af) >= (unsigned)(t+1))))
        __builtin_amdgcn_s_sleep(1);
    }
    __syncthreads();

    // ---- stage w_t -> LDS (coherent, batched) ----
    {
      f4 v0,v1,v2,v3;
      int u0=tid, u1=tid+512, u2=tid+1024, u3=tid+1536;
      ldg4(v0, &wS[(u0>>5)*128+(u0&31)*4]);
      ldg4(v1, &wS[(u1>>5)*128+(u1&31)*4]);
      ldg4(v2, &wS[(u2>>5)*128+(u2&31)*4]);
      ldg4(v3, &wS[(u3>>5)*128+(u3&31)*4]);
      waitv0();
      *(f4*)&wLs[(u0>>5)*132+(u0&31)*4] = v0;
      *(f4*)&wLs[(u1>>5)*132+(u1&31)*4] = v1;
      *(f4*)&wLs[(u2>>5)*132+(u2&31)*4] = v2;
      *(f4*)&wLs[(u3>>5)*132+(u3&31)*4] = v3;
    }
    __syncthreads();

    // ---- L1 w+x part (A-mapping) + L2/L0 x+w parts (C-mapping) ----
    {
      const float* wr1[8];
      #pragma unroll
      for (int s = 0; s < 8; ++s) {
        int rr = rh*8+s;
        int r = __builtin_amdgcn_readfirstlane((rr>>2)*H_ + ns + (rr&3));
        wr1[s] = Wih1 + (size_t)r*531;
        if (kq == 0) acc1[s] += bias1[r];
      }
      if (kq == 0) {
        float x0 = xT[(t*3+0)*64+lane], x1 = xT[(t*3+1)*64+lane], x2 = xT[(t*3+2)*64+lane];
        #pragma unroll
        for (int s = 0; s < 8; ++s)
          acc1[s] += x0*wr1[s][0] + x1*wr1[s][1] + x2*wr1[s][2];
      }
      for (int f = kq*8; f < kq*8+8; ++f) {
        f4 w4 = *(const f4*)&wLs[lane*132 + f*4];
        #pragma unroll
        for (int s = 0; s < 8; ++s) {
          const float* wp = wr1[s] + 3 + f*4;
          acc1[s] += w4.x*wp[0] + w4.y*wp[1] + w4.z*wp[2] + w4.w*wp[3];
        }
      }
      const float* wr2[8]; const float* wr0[8];
      #pragma unroll
      for (int s = 0; s < 8; ++s) {
        int rr = rh2*8+s;
        int r = __builtin_amdgcn_readfirstlane((rr>>2)*H_ + ns + (rr&3));
        wr2[s] = Wih2 + (size_t)r*531;
        wr0[s] = Wih0 + (size_t)r*131;
        if (kc == 0) { acc2[s] = bias2[r]; acc0[s] = bias0[r]; }
        else         { acc2[s] = 0.f;      acc0[s] = 0.f; }
      }
      if (kc == 0) {
        int tn = (t < T_-1) ? t+1 : t;
        float x0 = xT[(t*3+0)*64+lane], x1 = xT[(t*3+1)*64+lane], x2 = xT[(t*3+2)*64+lane];
        float y0 = xT[(tn*3+0)*64+lane], y1 = xT[(tn*3+1)*64+lane], y2 = xT[(tn*3+2)*64+lane];
        #pragma unroll
        for (int s = 0; s < 8; ++s) {
          acc2[s] += x0*wr2[s][0] + x1*wr2[s][1] + x2*wr2[s][2];
          acc0[s] += y0*wr0[s][0] + y1*wr0[s][1] + y2*wr0[s][2];
        }
      }
      for (int f = kc*8; f < kc*8+8; ++f) {
        f4 w4 = *(const f4*)&wLs[lane*132 + f*4];
        #pragma unroll
        for (int s = 0; s < 8; ++s) {
          const float* wp2 = wr2[s] + 3 + f*4;
          acc2[s] += w4.x*wp2[0] + w4.y*wp2[1] + w4.z*wp2[2] + w4.w*wp2[3];
          const float* wp0 = wr0[s] + 3 + f*4;
          acc0[s] += w4.x*wp0[0] + w4.y*wp0[1] + w4.z*wp0[2] + w4.w*wp0[3];
        }
      }
      #pragma unroll
      for (int s = 0; s < 8; ++s)
        pLs[((rh*4+kq)*8+s)*64+lane] = acc1[s];
    }
    __syncthreads();

    // ---- combine1 -> n0h (coherent x4), a0, n0c ----
    if (tid < 64) {
      const int b = tid;
      float hv[4];
      #pragma unroll
      for (int nl = 0; nl < 4; ++nl) {
        float g[4];
        #pragma unroll
        for (int q = 0; q < 4; ++q) {
          int rr = q*4+nl, rhh = rr>>3, s = rr&7;
          float v = 0.f;
          #pragma unroll
          for (int k2 = 0; k2 < 4; ++k2) v += pLs[((rhh*4+k2)*8+s)*64+b];
          g[q] = v;
        }
        float cp = n1c[(ns+nl)*64+b];
        float cn = sigf(g[1])*cp + sigf(g[0])*tanhf(g[2]);
        n0c[(ns+nl)*64+b] = cn;
        hv[nl] = sigf(g[3])*tanhf(cn);
      }
      f4 o = {hv[0],hv[1],hv[2],hv[3]};
      stg4(&n0h[b*400+ns], o);
      uint2 pk;
      pk.x = (bfu(hv[1])<<16) | bfu(hv[0]);
      pk.y = (bfu(hv[3])<<16) | bfu(hv[2]);
      *(uint2*)(a0 + ((size_t)t*64+b)*400 + ns) = pk;
    }
    gbar(ctrl, bid, ++tgt, tid, lane, wv);

    // =================== phase C ===================
    stage_h(n0h, hLs, tid);                  // n0h -> LDS (feeds L2 and L0')
    __syncthreads();

    // ---- LSTM2 h-part (all 8 waves, C-mapping) ----
    {
      const float* wr[8];
      #pragma unroll
      for (int s = 0; s < 8; ++s) {
        int rr = rh2*8+s;
        int r = __builtin_amdgcn_readfirstlane((rr>>2)*H_ + ns + (rr&3));
        wr[s] = Wih2 + (size_t)r*531 + 131;
      }
      for (int jc = kc*25; jc < kc*25+25; ++jc) {
        f4 hv = *(const f4*)&hLs[lane*404 + jc*4];
        #pragma unroll
        for (int s = 0; s < 8; ++s) {
          const float* wp = wr[s] + jc*4;
          acc2[s] += hv.x*wp[0] + hv.y*wp[1] + hv.z*wp[2] + hv.w*wp[3];
        }
      }
      #pragma unroll
      for (int s = 0; s < 8; ++s)
        pLs[((rh2*4+kc)*8+s)*64+lane] = acc2[s];
    }
    __syncthreads();

    // ---- combine2 -> n1h, a1, n1c ----
    if (tid < 64) {
      const int b = tid;
      float hv[4];
      #pragma unroll
      for (int nl = 0; nl < 4; ++nl) {
        float g[4];
        #pragma unroll
        for (int q = 0; q < 4; ++q) {
          int rr = q*4+nl, rhh = rr>>3, s = rr&7;
          float v = 0.f;
          #pragma unroll
          for (int k2 = 0; k2 < 4; ++k2) v += pLs[((rhh*4+k2)*8+s)*64+b];
          g[q] = v;
        }
        float cn = sigf(g[1])*c2c[ns+nl] + sigf(g[0])*tanhf(g[2]);
        n1c[(ns+nl)*64+b] = cn;
        hv[nl] = sigf(g[3])*tanhf(cn);
      }
      f4 o = {hv[0],hv[1],hv[2],hv[3]};
      stg4(&n1h[b*400+ns], o);
      uint2 pk;
      pk.x = (bfu(hv[1])<<16) | bfu(hv[0]);
      pk.y = (bfu(hv[3])<<16) | bfu(hv[2]);
      *(uint2*)(a1 + ((size_t)t*64+b)*400 + ns) = pk;
    }
    __syncthreads();                          // pLs reuse guard

    // ---- LSTM0' h-part (pipelined next-step LSTM0) ----
    if (t < T_-1) {
      const float* wr[8];
      #pragma unroll
      for (int s = 0; s < 8; ++s) {
        int rr = rh2*8+s;
        int r = __builtin_amdgcn_readfirstlane((rr>>2)*H_ + ns + (rr&3));
        wr[s] = Whh0 + (size_t)r*400;
      }
      for (int jc = kc*25; jc < kc*25+25; ++jc) {
        f4 hv = *(const f4*)&hLs[lane*404 + jc*4];
        #pragma unroll
        for (int s = 0; s < 8; ++s) {
          const float* wp = wr[s] + jc*4;
          acc0[s] += hv.x*wp[0] + hv.y*wp[1] + hv.z*wp[2] + hv.w*wp[3];
        }
      }
      #pragma unroll
      for (int s = 0; s < 8; ++s)
        pLs[((rh2*4+kc)*8+s)*64+lane] = acc0[s];
      __syncthreads();
      if (tid < 64) {
        const int b = tid;
        float hv[4];
        #pragma unroll
        for (int nl = 0; nl < 4; ++nl) {
          float g[4];
          #pragma unroll
          for (int q = 0; q < 4; ++q) {
            int rr = q*4+nl, rhh = rr>>3, s = rr&7;
            float v = 0.f;
            #pragma unroll
            for (int k2 = 0; k2 < 4; ++k2) v += pLs[((rhh*4+k2)*8+s)*64+b];
            g[q] = v;
          }
          float cp = n0c[(ns+nl)*64+b];
          float cn = sigf(g[1])*cp + sigf(g[0])*tanhf(g[2]);
          hv[nl] = sigf(g[3])*tanhf(cn);
        }
        f4 o = {hv[0],hv[1],hv[2],hv[3]};
        stg4(&hA[b*400+ns], o);
      }
    }
    gbar(ctrl, bid, ++tgt, tid, lane, wv);
  }
}

// ---------------- output projection + MDN/eos loss ----------------
__global__ __launch_bounds__(NTHR) void k_outloss(
  const float* __restrict__ Wo, const float* __restrict__ strokes, float* __restrict__ ws)
{
  __shared__ __align__(16) float hL4[64*404];
  __shared__ float oL[121*65];
  const int t = blockIdx.x;
  const int tid = threadIdx.x;
  const int lane = tid & 63;
  const int wv = __builtin_amdgcn_readfirstlane(tid >> 6);
  const float* ob = ws + OF_OB;
  const unsigned* src0 = (const unsigned*)(ws + OF_A0) + (size_t)t*12800;
  const unsigned* src1 = (const unsigned*)(ws + OF_A1) + (size_t)t*12800;

  float acc[16];
  #pragma unroll
  for (int s = 0; s < 16; ++s) { int r = wv + 8*s; acc[s] = (r < 121) ? ob[r] : 0.f; }

  for (int i = tid; i < 12800; i += NTHR) {
    unsigned v = src0[i];
    int b = i/200, jc = i - b*200;
    hL4[b*404+jc*2+0] = __uint_as_float(v << 16);
    hL4[b*404+jc*2+1] = __uint_as_float(v & 0xffff0000u);
  }
  __syncthreads();
  for (int jc = 0; jc < 100; ++jc) {
    f4 hv = *(const f4*)&hL4[lane*404+jc*4];
    #pragma unroll
    for (int s = 0; s < 16; ++s) {
      int r = wv + 8*s;
      if (r < 121) {
        const float* wp = Wo + (size_t)r*1200 + jc*4;
        acc[s] += hv.x*wp[0] + hv.y*wp[1] + hv.z*wp[2] + hv.w*wp[3];
      }
    }
  }
  __syncthreads();
  for (int i = tid; i < 12800; i += NTHR) {
    unsigned v = src1[i];
    int b = i/200, jc = i - b*200;
    hL4[b*404+jc*2+0] = __uint_as_float(v << 16);
    hL4[b*404+jc*2+1] = __uint_as_float(v & 0xffff0000u);
  }
  __syncthreads();
  for (int jc = 0; jc < 100; ++jc) {
    f4 hv = *(const f4*)&hL4[lane*404+jc*4];
    #pragma unroll
    for (int s = 0; s < 16; ++s) {
      int r = wv + 8*s;
      if (r < 121) {
        const float* wp = Wo + (size_t)r*1200 + 400 + jc*4;
        acc[s] += hv.x*wp[0] + hv.y*wp[1] + hv.z*wp[2] + hv.w*wp[3];
      }
    }
  }
  #pragma unroll
  for (int s = 0; s < 16; ++s) { int r = wv + 8*s; if (r < 121) oL[r*65+lane] = acc[s]; }
  __syncthreads();

  if (wv == 0) {
    const int b = lane;
    float x0 = strokes[(b*T_+t)*3+0];
    float x1 = strokes[(b*T_+t)*3+1];
    float y  = strokes[(b*T_+t)*3+2];
    float mp = -1e30f;
    #pragma unroll
    for (int k = 0; k < 20; ++k) mp = fmaxf(mp, oL[(80+k)*65+b]);
    float sp = 0.f;
    #pragma unroll
    for (int k = 0; k < 20; ++k) sp += expf(oL[(80+k)*65+b] - mp);
    float lsep = mp + logf(sp);
    float sk[20]; float ms = -1e30f;
    #pragma unroll
    for (int k = 0; k < 20; ++k) {
      float mu0 = oL[(2*k)*65+b],    mu1 = oL[(2*k+1)*65+b];
      float l0  = oL[(40+2*k)*65+b], l1  = oL[(41+2*k)*65+b];
      float rho = tanhf(oL[(100+k)*65+b]);
      float t0 = (x0-mu0)*expf(-l0);
      float t1 = (x1-mu1)*expf(-l1);
      float on = 1.f - rho*rho;
      float Z = t0*t0 + t1*t1 - 2.f*rho*t0*t1;
      float logN = -Z/(2.f*on) - (1.8378770664093453f + l0 + l1 + 0.5f*logf(on));
      float sv = (oL[(80+k)*65+b] - lsep) + logN;
      sk[k] = sv; ms = fmaxf(ms, sv);
    }
    float ss = 0.f;
    #pragma unroll
    for (int k = 0; k < 20; ++k) ss += expf(sk[k]-ms);
    float stroke = -(ms + logf(ss));
    float z = oL[120*65+b];
    float eos = fmaxf(z,0.f) - z*y + log1pf(expf(-fabsf(z)));
    #pragma unroll
    for (int off = 32; off > 0; off >>= 1) {
      stroke += __shfl_down(stroke, off, 64);
      eos    += __shfl_down(eos, off, 64);
    }
    if (lane == 0) { atomicAdd(ws+OF_LOSS, stroke); atomicAdd(ws+OF_LOSS+1, eos); }
  }
}

__global__ void k_fin(const float* __restrict__ ws, float* __restrict__ out) {
  if (threadIdx.x == 0) {
    out[0] = ws[OF_LOSS]   * (1.f/25600.f);
    out[1] = ws[OF_LOSS+1] * (1.f/25600.f);
  }
}

// ---------------- host ----------------
extern "C" void kernel_launch(void* const* d_in, const int* in_sizes, int n_in,
                              void* d_out, int out_size, void* d_ws, size_t ws_size,
                              hipStream_t stream) {
  const float* strokes = (const float*)d_in[0];
  const int*   chars   = (const int*)d_in[1];
  const float* cmask   = (const float*)d_in[2];
  const float* emb     = (const float*)d_in[3];
  const float* Wih0    = (const float*)d_in[4];
  const float* Whh0    = (const float*)d_in[5];
  const float* bih0    = (const float*)d_in[6];
  const float* bhh0    = (const float*)d_in[7];
  const float* Wih1    = (const float*)d_in[8];
  const float* Whh1    = (const float*)d_in[9];
  const float* bih1    = (const float*)d_in[10];
  const float* bhh1    = (const float*)d_in[11];
  const float* Wih2    = (const float*)d_in[12];
  const float* Whh2    = (const float*)d_in[13];
  const float* bih2    = (const float*)d_in[14];
  const float* bhh2    = (const float*)d_in[15];
  const float* Wa      = (const float*)d_in[16];
  const float* ba      = (const float*)d_in[17];
  const float* Wo      = (const float*)d_in[18];
  const float* bo      = (const float*)d_in[19];
  const float* h0      = (const float*)d_in[20];
  const float* c0      = (const float*)d_in[21];
  const float* w0      = (const float*)d_in[22];
  const float* k0      = (const float*)d_in[23];
  float* ws = (float*)d_ws;
  float* out = (float*)d_out;
  if (ws_size < WS_FLOATS*sizeof(float)) return;  // ~42 MB required

  hipMemsetAsync(d_ws, 0, 32768, stream);  // control words + loss accumulators
  k_pre<<<256, 256, 0, stream>>>(strokes, chars, cmask, emb, Wih1, Whh2, Wo,
                                 bih0, bhh0, bih1, bhh1, bih2, bhh2, bo,
                                 h0, c0, w0, k0, ws);
  k_init<<<50, 512, 0, stream>>>(Wih0, Whh0, h0, c0, w0, ws);
  k_scan<<<NBLK, NTHR, 0, stream>>>(Wih0, Whh0, Wih1, Whh1, Wih2, Wa, ba, c0, ws);
  k_outloss<<<T_, NTHR, 0, stream>>>(Wo, strokes, ws);
  k_fin<<<1, 64, 0, stream>>>(ws, out);
}